// Round 17
// baseline (446.865 us; speedup 1.0000x reference)
//
#include <hip/hip_runtime.h>
#include <hip/hip_bf16.h>

// HGNNP_GCN + ClusterNet forward, MI355X (round 17).
// R16 counters: k_pB 58us, FETCH 96.5MB vs ~16MB compulsory -> gather is
// L2-capacity-miss bound (12.8MB src cycles through 4MB per-XCD L2). This
// round: source-windowed multi-pass gathers. Wave keeps acc in registers and
// sweeps its CSR list NPASS times, accepting only src in the current ~3.2MB
// window (wave-uniform range test -> no divergence). NPASS: 4 for 12.8MB
// sources, 2 for 6.4MB, 1 for L2-resident ones.

#define NN   50000
#define NP   50048   // padded rows (782 * 64)
#define EE   800000
#define NINC 200000
#define NEH  10000
#define KCL  10
#define CBLK 782     // ceil(NN/64)

#define MU_OFF  0
#define R_OFF   640
#define EMB_OFF 500640
#define D_OFF   3700640

typedef __hip_bfloat16 bf16;
typedef unsigned short u16;
typedef unsigned int   u32;
typedef __attribute__((ext_vector_type(8))) short short8;
typedef __attribute__((ext_vector_type(4))) float f32x4;

__device__ __forceinline__ float b2f(bf16 v){ return __bfloat162float(v); }
__device__ __forceinline__ float us2f(u16 u){ return __uint_as_float(((unsigned)u) << 16); }
__device__ __forceinline__ u16 f2bu(float f){
  unsigned u = __float_as_uint(f);
  return (u16)((u + 0x7fffu + ((u >> 16) & 1u)) >> 16);   // RNE
}
__device__ __forceinline__ bf16 f2b(float f){
  u16 r = f2bu(f);
  bf16 h;
  reinterpret_cast<u16&>(h) = r;
  return h;
}
__device__ __forceinline__ float ldf(const void* p, size_t i, int isbf){
  return isbf ? b2f(((const bf16*)p)[i]) : ((const float*)p)[i];
}
__device__ __forceinline__ void stf(void* p, size_t i, float v, int isbf){
  if (isbf) ((bf16*)p)[i] = f2b(v);
  else      ((float*)p)[i] = v;
}

// ---------------- dtype detector ----------------
__global__ void k_detect(const u16* __restrict__ xr, int* flag){
  __shared__ int bad;
  if (threadIdx.x == 0) bad = 0;
  __syncthreads();
  for (int i = threadIdx.x; i < 4096; i += 256){
    int e = (xr[i] >> 7) & 0xFF;
    if (e >= 0xEF) bad = 1;
  }
  __syncthreads();
  if (threadIdx.x == 0) *flag = bad ? 0 : 1;   // 1 = bf16, 0 = f32
}

// ---------------- fused input prep ----------------
__global__ __launch_bounds__(256) void k_prep(const void* __restrict__ x, u16* __restrict__ xb,
    const void* gW1, const void* hW1, const void* gW2, const void* hW2,
    const void* gb1, const void* hb1, const void* gb2, const void* hb2,
    u16* gW1t, u16* hW1t, u16* gW2t, u16* hW2t,
    float* gb1f, float* hb1f, float* gb2f, float* hb2f,
    const int* __restrict__ flag){
  const int isbf = flag[0];
  const int blk = blockIdx.x;
  if (blk < 12500){
    int i = blk*256 + threadIdx.x;
    ushort4 o;
    if (isbf){
      o = ((const ushort4*)x)[i];
    } else {
      float4 v = ((const float4*)x)[i];
      o = make_ushort4(f2bu(v.x), f2bu(v.y), f2bu(v.z), f2bu(v.w));
    }
    ((ushort4*)xb)[i] = o;
  } else {
    int i = (blk - 12500)*256 + threadIdx.x;
    if (i < 256*128){
      int n = i >> 8, k = i & 255;
      gW1t[i] = f2bu(ldf(gW1, (size_t)k*128 + n, isbf));
      hW1t[i] = f2bu(ldf(hW1, (size_t)k*128 + n, isbf));
    }
    if (i < 64*128){
      int n = i >> 7, k = i & 127;
      gW2t[i] = f2bu(ldf(gW2, (size_t)k*64 + n, isbf));
      hW2t[i] = f2bu(ldf(hW2, (size_t)k*64 + n, isbf));
    }
    if (i < 128){ gb1f[i] = ldf(gb1,i,isbf); hb1f[i] = ldf(hb1,i,isbf); }
    if (i < 64) { gb2f[i] = ldf(gb2,i,isbf); hb2f[i] = ldf(hb2,i,isbf); }
  }
}

// ---------------- fused CSR build ----------------
__global__ __launch_bounds__(256) void k_hist_all(const int* __restrict__ dstp,
    const int* __restrict__ hv, const int* __restrict__ he,
    int* HAg, int* HAv, int* HAe){
  __shared__ u32 hist[250];
  const int blk = blockIdx.x;
  const int* key; int* HA; int chunk, npb, lb;
  if (blk < 128){ key=dstp; HA=HAg; chunk=6250; npb=200; lb=blk; }
  else if (blk < 192){ key=hv; HA=HAv; chunk=3125; npb=200; lb=blk-128; }
  else { key=he; HA=HAe; chunk=3125; npb=40; lb=blk-192; }
  for (int i = threadIdx.x; i < 250; i += 256) hist[i] = 0;
  __syncthreads();
  int base = lb*chunk;
  for (int i = threadIdx.x; i < chunk; i += 256)
    atomicAdd(&hist[key[base+i]/npb], 1u);
  __syncthreads();
  int* out = HA + lb*250;
  for (int i = threadIdx.x; i < 250; i += 256) out[i] = (int)hist[i];
}

__global__ void k_scanA_all(int* HAg, int* HAv, int* HAe,
                            int* bsg, int* bsv, int* bse){
  int* HA; int* bs; int nch;
  if (blockIdx.x == 0){ HA = HAg; bs = bsg; nch = 128; }
  else if (blockIdx.x == 1){ HA = HAv; bs = bsv; nch = 64; }
  else { HA = HAe; bs = bse; nch = 64; }
  __shared__ int s[256];
  int t = threadIdx.x;
  int run = 0;
  if (t < 250){
    for (int c = 0; c < nch; ++c){
      int v = HA[c*250 + t];
      HA[c*250 + t] = run;
      run += v;
    }
  }
  int own = (t < 250) ? run : 0;
  s[t] = own; __syncthreads();
  #pragma unroll
  for (int off = 1; off < 256; off <<= 1){
    int add = (t >= off) ? s[t-off] : 0;
    __syncthreads();
    s[t] += add;
    __syncthreads();
  }
  if (t < 250) bs[t] = s[t] - own;
  if (t == 255) bs[250] = s[255];
}

__global__ __launch_bounds__(256) void k_fillA_all(const int* __restrict__ dstp,
    const int* __restrict__ srcp, const int* __restrict__ hv, const int* __restrict__ he,
    const int* HAg, const int* HAv, const int* HAe,
    const int* bsg, const int* bsv, const int* bse,
    u32* pg, u32* pv, u32* pe){
  __shared__ u32 cur[250];
  const int blk = blockIdx.x;
  const int* key; const int* val; const int* HA; const int* bs; u32* packed;
  int chunk, npb, lb;
  if (blk < 128){ key=dstp; val=srcp; HA=HAg; bs=bsg; packed=pg; chunk=6250; npb=200; lb=blk; }
  else if (blk < 192){ key=hv; val=he; HA=HAv; bs=bsv; packed=pv; chunk=3125; npb=200; lb=blk-128; }
  else { key=he; val=hv; HA=HAe; bs=bse; packed=pe; chunk=3125; npb=40; lb=blk-192; }
  const int* pre = HA + lb*250;
  for (int i = threadIdx.x; i < 250; i += 256) cur[i] = (u32)(bs[i] + pre[i]);
  __syncthreads();
  int base = lb*chunk;
  for (int i = threadIdx.x; i < chunk; i += 256){
    int k = key[base+i];
    int b = k / npb;
    u32 pos = atomicAdd(&cur[b], 1u);
    packed[pos] = ((u32)(k - b*npb) << 16) | (u32)val[base+i];
  }
}

__global__ __launch_bounds__(256) void k_fillB_all(
    const u32* pg, const u32* pv, const u32* pe,
    const int* bsg, const int* bsv, const int* bse,
    int* csr_g, int* csr_v, int* csr_e,
    int* cg, int* cv, int* ce, int* rp_g, int* rp_v, int* rp_e,
    float* dinv, float* invv, float* inve){
  __shared__ u32 hist[200];
  __shared__ int s[256];
  __shared__ u32 cur[200];
  const int blk = blockIdx.x;
  const u32* packed; const int* bs; int* csr; int* cnt; int* rp; int npb, b, mode;
  if (blk < 250){ packed=pg; bs=bsg; csr=csr_g; cnt=cg; rp=rp_g; npb=200; b=blk; mode=0; }
  else if (blk < 500){ packed=pv; bs=bsv; csr=csr_v; cnt=cv; rp=rp_v; npb=200; b=blk-250; mode=1; }
  else { packed=pe; bs=bse; csr=csr_e; cnt=ce; rp=rp_e; npb=40; b=blk-500; mode=2; }
  const int s0 = bs[b], m = bs[b+1] - s0;
  const int t = threadIdx.x;
  for (int i = t; i < npb; i += 256) hist[i] = 0;
  __syncthreads();
  for (int i = t; i < m; i += 256)
    atomicAdd(&hist[packed[s0+i] >> 16], 1u);
  __syncthreads();
  int own = (t < npb) ? (int)hist[t] : 0;
  s[t] = own; __syncthreads();
  #pragma unroll
  for (int off = 1; off < 256; off <<= 1){
    int add = (t >= off) ? s[t-off] : 0;
    __syncthreads();
    s[t] += add;
    __syncthreads();
  }
  if (t < npb){
    int excl = s[t] - own;
    int node = b*npb + t;
    cnt[node] = own;
    rp[node]  = s0 + excl;
    cur[t] = (u32)(s0 + excl);
    if (mode == 0)      dinv[node] = rsqrtf(1.0f + (float)own);
    else if (mode == 1) invv[node] = 1.0f / fmaxf((float)own, 1.0f);
    else                inve[node] = 1.0f / fmaxf((float)own, 1.0f);
  }
  if (mode == 0 && b == 249 && t < NP - NN) dinv[NN + t] = 0.f;  // pad rows
  __syncthreads();
  for (int i = t; i < m; i += 256){
    u32 p = packed[s0+i];
    u32 pos = atomicAdd(&cur[p >> 16], 1u);
    csr[pos] = (int)(p & 0xffffu);
  }
}

// ---------------- MFMA GEMM body ----------------
template<int KDIM, int NCOL>
__device__ __forceinline__ void gemm_body(const u16* __restrict__ A,
    const u16* __restrict__ Wt, const float* __restrict__ bias,
    const float* __restrict__ rowscale, u16* __restrict__ C, int relu, int bid)
{
  constexpr int NT  = NCOL/16;
  constexpr int LDA = 40;
  __shared__ __align__(16) u16 Asl[64][LDA];
  __shared__ __align__(16) u16 Wsl[NCOL][LDA];
  const int tid  = threadIdx.x;
  const int wave = tid >> 6, lane = tid & 63;
  const int l15 = lane & 15, l4 = lane >> 4;
  const int row0 = bid * 64;
  const int ar = tid >> 2, aq = tid & 3;
  constexpr int NW = NCOL*4/256;

  f32x4 acc[NT] = {};

  for (int kk = 0; kk < KDIM; kk += 32){
    {
      uint4 v = *(const uint4*)(A + (size_t)(row0 + ar)*KDIM + kk + aq*8);
      *(uint4*)&Asl[ar][aq*8] = v;
    }
    #pragma unroll
    for (int w2 = 0; w2 < NW; ++w2){
      int c = tid + w2*256;
      int n = c >> 2, q = c & 3;
      uint4 v = *(const uint4*)(Wt + (size_t)n*KDIM + kk + q*8);
      *(uint4*)&Wsl[n][q*8] = v;
    }
    __syncthreads();
    short8 af = *(const short8*)&Asl[wave*16 + l15][l4*8];
    #pragma unroll
    for (int t = 0; t < NT; ++t){
      short8 bf = *(const short8*)&Wsl[t*16 + l15][l4*8];
      acc[t] = __builtin_amdgcn_mfma_f32_16x16x32_bf16(af, bf, acc[t], 0, 0, 0);
    }
    __syncthreads();
  }

  #pragma unroll
  for (int t = 0; t < NT; ++t){
    int gcol = t*16 + l15;
    float b = bias ? bias[gcol] : 0.f;
    #pragma unroll
    for (int e = 0; e < 4; ++e){
      int grow = row0 + wave*16 + l4*4 + e;
      float v = acc[t][e] + b;
      if (relu) v = fmaxf(v, 0.f);
      if (rowscale) v *= rowscale[grow];
      C[(size_t)grow*NCOL + gcol] = f2bu(v);
    }
  }
}

// ---------------- gather body: wave/row, NPASS source windows ----------------
template<int F, bool OUTBF, bool SELF, int NPASS>
__device__ __forceinline__ void gather_body(const int* __restrict__ rp,
    const int* __restrict__ cnt, const int* __restrict__ csr,
    const float* __restrict__ scale, const u16* __restrict__ h,
    const float* __restrict__ bias, void* __restrict__ out, int relu,
    int bid, int wpass)
{
  const int wave = threadIdx.x >> 6, lane = threadIdx.x & 63;
  const int d = bid*4 + wave;
  const int k0 = rp[d], n = cnt[d];

  if constexpr (F == 128){
    const uint* h32 = (const uint*)h;
    float a0=0,a1=0,b0=0,b1=0,c0=0,c1=0,e0=0,e1=0;
    if (SELF){
      uint v = h32[(size_t)d*64 + lane];
      a0 = us2f((u16)v); a1 = us2f((u16)(v>>16));
    }
    #pragma unroll 1
    for (int p = 0; p < NPASS; ++p){
      const int lo = p*wpass;
      for (int base = 0; base < n; base += 64){
        int mm = n - base; if (mm > 64) mm = 64;
        int idx = (lane < mm) ? csr[k0 + base + lane] : 0;
        int jj = 0;
        for (; jj + 4 <= mm; jj += 4){
          int s0=__shfl(idx,jj), s1=__shfl(idx,jj+1), s2=__shfl(idx,jj+2), s3=__shfl(idx,jj+3);
          if (NPASS==1 || (u32)(s0-lo) < (u32)wpass){
            uint v = h32[(size_t)s0*64 + lane];
            a0 += us2f((u16)v); a1 += us2f((u16)(v>>16));
          }
          if (NPASS==1 || (u32)(s1-lo) < (u32)wpass){
            uint v = h32[(size_t)s1*64 + lane];
            b0 += us2f((u16)v); b1 += us2f((u16)(v>>16));
          }
          if (NPASS==1 || (u32)(s2-lo) < (u32)wpass){
            uint v = h32[(size_t)s2*64 + lane];
            c0 += us2f((u16)v); c1 += us2f((u16)(v>>16));
          }
          if (NPASS==1 || (u32)(s3-lo) < (u32)wpass){
            uint v = h32[(size_t)s3*64 + lane];
            e0 += us2f((u16)v); e1 += us2f((u16)(v>>16));
          }
        }
        for (; jj < mm; ++jj){
          int s = __shfl(idx, jj);
          if (NPASS==1 || (u32)(s-lo) < (u32)wpass){
            uint v = h32[(size_t)s*64 + lane];
            a0 += us2f((u16)v); a1 += us2f((u16)(v>>16));
          }
        }
      }
    }
    float sc = scale[d];
    float o0 = ((a0+b0)+(c0+e0))*sc;
    float o1 = ((a1+b1)+(c1+e1))*sc;
    if (bias){ o0 += bias[lane*2]; o1 += bias[lane*2+1]; }
    if (relu){ o0 = fmaxf(o0,0.f); o1 = fmaxf(o1,0.f); }
    if (OUTBF){
      ((uint*)out)[(size_t)d*64 + lane] = (uint)f2bu(o0) | ((uint)f2bu(o1) << 16);
    } else {
      ((float2*)out)[(size_t)d*64 + lane] = make_float2(o0, o1);
    }
  } else { // F == 64
    float a=0,b=0,c=0,e=0;
    if (SELF) a = us2f(h[(size_t)d*64 + lane]);
    #pragma unroll 1
    for (int p = 0; p < NPASS; ++p){
      const int lo = p*wpass;
      for (int base = 0; base < n; base += 64){
        int mm = n - base; if (mm > 64) mm = 64;
        int idx = (lane < mm) ? csr[k0 + base + lane] : 0;
        int jj = 0;
        for (; jj + 4 <= mm; jj += 4){
          int s0=__shfl(idx,jj), s1=__shfl(idx,jj+1), s2=__shfl(idx,jj+2), s3=__shfl(idx,jj+3);
          if (NPASS==1 || (u32)(s0-lo) < (u32)wpass) a += us2f(h[(size_t)s0*64 + lane]);
          if (NPASS==1 || (u32)(s1-lo) < (u32)wpass) b += us2f(h[(size_t)s1*64 + lane]);
          if (NPASS==1 || (u32)(s2-lo) < (u32)wpass) c += us2f(h[(size_t)s2*64 + lane]);
          if (NPASS==1 || (u32)(s3-lo) < (u32)wpass) e += us2f(h[(size_t)s3*64 + lane]);
        }
        for (; jj < mm; ++jj){
          int s = __shfl(idx, jj);
          if (NPASS==1 || (u32)(s-lo) < (u32)wpass) a += us2f(h[(size_t)s*64 + lane]);
        }
      }
    }
    float o = ((a+b)+(c+e))*scale[d];
    if (bias) o += bias[lane];
    if (relu) o = fmaxf(o, 0.f);
    if (OUTBF) ((u16*)out)[(size_t)d*64 + lane] = f2bu(o);
    else       ((float*)out)[(size_t)d*64 + lane] = o;
  }
}

// ---------------- phase kernels ----------------
__global__ __launch_bounds__(256) void k_pA(const u16* xb, const u16* gW1t,
    const float* dinv, u16* BAb){
  gemm_body<256,128>(xb, gW1t, nullptr, dinv, BAb, 0, blockIdx.x);
}
// GEMM_h1 (782) || gather_gcn1 (12500, 4-pass over 12.8MB BAb)
__global__ __launch_bounds__(256) void k_pB(const u16* xb, const u16* hW1t,
    const float* hb1f, u16* BEb,
    const int* rp_g, const int* cg, const int* csr_g, const float* dinv,
    const u16* BAb, const float* gb1f, u16* BBb){
  if (blockIdx.x < 782) gemm_body<256,128>(xb, hW1t, hb1f, nullptr, BEb, 0, blockIdx.x);
  else gather_body<128,true,true,4>(rp_g, cg, csr_g, dinv, BAb, gb1f, BBb, 1,
                                    blockIdx.x - 782, NP/4);
}
// GEMM_g2 (782) || gather_e1 (2500, 4-pass over 12.8MB BEb)
__global__ __launch_bounds__(256) void k_pC(const u16* BBb, const u16* gW2t,
    const float* dinv, u16* BAb,
    const int* rp_e, const int* ce, const int* csr_e, const float* inve,
    const u16* BEb, u16* BDb){
  if (blockIdx.x < 782) gemm_body<128,64>(BBb, gW2t, nullptr, dinv, BAb, 0, blockIdx.x);
  else gather_body<128,true,false,4>(rp_e, ce, csr_e, inve, BEb, nullptr, BDb, 0,
                                     blockIdx.x - 782, NP/4);
}
// gather_v1 (12500, 1-pass 2.56MB BDb) || gather_gcn2 (12500, 2-pass 6.4MB BAb)
__global__ __launch_bounds__(256) void k_pD(
    const int* rp_v, const int* cv, const int* csr_v, const float* invv,
    const u16* BDb, u16* BCb,
    const int* rp_g, const int* cg, const int* csr_g, const float* dinv,
    const u16* BAb, const float* gb2f, float* x2f){
  if (blockIdx.x < 12500)
    gather_body<128,true,false,1>(rp_v, cv, csr_v, invv, BDb, nullptr, BCb, 1,
                                  blockIdx.x, NEH);
  else
    gather_body<64,false,true,2>(rp_g, cg, csr_g, dinv, BAb, gb2f, x2f, 0,
                                 blockIdx.x - 12500, NP/2);
}
__global__ __launch_bounds__(256) void k_pE(const u16* BCb, const u16* hW2t,
    const float* hb2f, u16* BEb){
  gemm_body<128,64>(BCb, hW2t, hb2f, nullptr, BEb, 0, blockIdx.x);
}
// gather_e2 (2500, 2-pass over 6.4MB BEb)
__global__ __launch_bounds__(256) void k_pF(const int* rp_e, const int* ce,
    const int* csr_e, const float* inve, const u16* BEb, u16* BDb){
  gather_body<64,true,false,2>(rp_e, ce, csr_e, inve, BEb, nullptr, BDb, 0,
                               blockIdx.x, NP/2);
}
// gather_v2 (12500, 1-pass 1.28MB BDb)
__global__ __launch_bounds__(256) void k_pG(const int* rp_v, const int* cv,
    const int* csr_v, const float* invv, const u16* BDb, float* x4f){
  gather_body<64,false,false,1>(rp_v, cv, csr_v, invv, BDb, nullptr, x4f, 0,
                                blockIdx.x, NEH);
}

// ---------------- embeds + row normalize ----------------
__global__ void k_embeds(const float* __restrict__ x2, const float* __restrict__ x4,
                         void* __restrict__ out, float* __restrict__ data,
                         const int* __restrict__ flag){
  int row  = blockIdx.x*4 + (threadIdx.x >> 6);
  int lane = threadIdx.x & 63;
  if (row >= NN) return;
  size_t idx = (size_t)row*64 + lane;
  float v = 0.5f*(x2[idx] + x4[idx]);
  float ss = v*v;
  #pragma unroll
  for (int off=32; off>0; off>>=1) ss += __shfl_xor(ss, off);
  float inv = rsqrtf(ss);
  data[idx] = v*inv;
  stf(out, EMB_OFF + idx, v, flag[0]);
}

// ---------------- clustering ----------------
__global__ void k_mu_init(const float* __restrict__ data, float* __restrict__ mu){
  int p = threadIdx.x;      // 640 threads, 1 block
  int k = p >> 6, f = p & 63;
  mu[p] = data[(size_t)k*(NN/KCL)*64 + f];
}

__global__ __launch_bounds__(640) void k_cluster_iter(const float* __restrict__ data,
    const float* __restrict__ mu, float* __restrict__ part, float* __restrict__ pcr,
    const int* __restrict__ nit, int iter)
{
  if (iter >= nit[0]) return;
  __shared__ float ms[640];
  __shared__ float dt[64][65];
  __shared__ float ds[64][11];
  const int tid = threadIdx.x;
  ms[tid] = mu[tid];
  const int base = blockIdx.x*64;
  for (int i = tid; i < 4096; i += 640){
    int r = i >> 6, f = i & 63;
    int grow = base + r;
    dt[r][f] = (grow < NN) ? data[(size_t)grow*64 + f] : 0.f;
  }
  __syncthreads();
  {
    const int row = tid & 63, k = tid >> 6;
    float dot = 0.f;
    #pragma unroll 16
    for (int f = 0; f < 64; ++f)
      dot = fmaf(dt[row][f], ms[k*64 + f], dot);
    ds[row][k] = dot;
  }
  __syncthreads();
  if (tid < 64){
    float dot[KCL];
    #pragma unroll
    for (int k = 0; k < KCL; ++k) dot[k] = ds[tid][k];
    float m = -1e30f;
    #pragma unroll
    for (int k = 0; k < KCL; ++k) m = fmaxf(m, 5.0f*dot[k]);
    float s = 0.f, ev[KCL];
    #pragma unroll
    for (int k = 0; k < KCL; ++k){ ev[k] = expf(5.0f*dot[k]-m); s += ev[k]; }
    float inv = (base + tid < NN) ? 1.0f/s : 0.f;
    #pragma unroll
    for (int k = 0; k < KCL; ++k) ds[tid][k] = ev[k]*inv;
  }
  __syncthreads();
  {
    const int f = tid & 63, k = tid >> 6;
    float acc = 0.f, crp = 0.f;
    #pragma unroll 8
    for (int t = 0; t < 64; ++t){
      float rv = ds[t][k];
      acc = fmaf(rv, dt[t][f], acc);
      crp += rv;
    }
    part[(size_t)blockIdx.x*640 + tid] = acc;
    if (f == 0) pcr[blockIdx.x*16 + k] = crp;
  }
}

__global__ void k_cred1(const float* __restrict__ part, const float* __restrict__ pcr,
                        float* __restrict__ p2, float* __restrict__ pc2,
                        const int* __restrict__ nit, int iter){
  if (iter >= nit[0]) return;
  int b = blockIdx.x, t = threadIdx.x;
  int r0 = b*20, r1 = r0 + 20; if (r1 > CBLK) r1 = CBLK;
  if (t < 640){
    float a = 0.f;
    for (int r = r0; r < r1; ++r) a += part[(size_t)r*640 + t];
    p2[(size_t)b*640 + t] = a;
  } else if (t < 640 + KCL){
    int k = t - 640;
    float a = 0.f;
    for (int r = r0; r < r1; ++r) a += pcr[r*16 + k];
    pc2[b*16 + k] = a;
  }
}

__global__ void k_cred2mu(const float* __restrict__ p2, const float* __restrict__ pc2,
                          float* __restrict__ mu, const int* __restrict__ nit, int iter){
  if (iter >= nit[0]) return;
  __shared__ float crs[16];
  int t = threadIdx.x;
  if (t >= 640 && t < 640 + KCL){
    int k = t - 640;
    float a = 0.f;
    #pragma unroll
    for (int b = 0; b < 40; ++b) a += pc2[b*16 + k];
    crs[k] = a;
  }
  __syncthreads();
  if (t < 640){
    float a = 0.f;
    #pragma unroll
    for (int b = 0; b < 40; ++b) a += p2[(size_t)b*640 + t];
    mu[t] = a / crs[t >> 6];
  }
}

__global__ __launch_bounds__(640) void k_cluster_final(const float* __restrict__ data,
    const float* __restrict__ mu, void* __restrict__ out, const int* __restrict__ flag)
{
  __shared__ float ms[640];
  __shared__ float dt[64][65];
  __shared__ float ds[64][11];
  const int tid = threadIdx.x;
  ms[tid] = mu[tid];
  const int base = blockIdx.x*64;
  for (int i = tid; i < 4096; i += 640){
    int r = i >> 6, f = i & 63;
    int grow = base + r;
    dt[r][f] = (grow < NN) ? data[(size_t)grow*64 + f] : 0.f;
  }
  __syncthreads();
  {
    const int row = tid & 63, k = tid >> 6;
    float dot = 0.f;
    #pragma unroll 16
    for (int f = 0; f < 64; ++f)
      dot = fmaf(dt[row][f], ms[k*64 + f], dot);
    ds[row][k] = dot;
  }
  __syncthreads();
  const int isbf = flag[0];
  if (blockIdx.x == 0) stf(out, MU_OFF + tid, ms[tid], isbf);
  if (tid < 64 && base + tid < NN){
    const int row = base + tid;
    float dot[KCL];
    #pragma unroll
    for (int k = 0; k < KCL; ++k) dot[k] = ds[tid][k];
    float m = -1e30f;
    #pragma unroll
    for (int k = 0; k < KCL; ++k) m = fmaxf(m, 5.0f*dot[k]);
    float s = 0.f, ev[KCL];
    #pragma unroll
    for (int k = 0; k < KCL; ++k){ ev[k] = expf(5.0f*dot[k]-m); s += ev[k]; }
    float inv = 1.0f/s;
    #pragma unroll
    for (int k = 0; k < KCL; ++k){
      stf(out, (size_t)D_OFF + (size_t)row*KCL + k, dot[k],    isbf);
      stf(out, (size_t)R_OFF + (size_t)row*KCL + k, ev[k]*inv, isbf);
    }
  }
}

// ---------------- launch ----------------
extern "C" void kernel_launch(void* const* d_in, const int* in_sizes, int n_in,
                              void* d_out, int out_size, void* d_ws, size_t ws_size,
                              hipStream_t stream)
{
  const void* x   = d_in[0];
  const int*  ei  = (const int*)d_in[1];
  const int*  hv  = (const int*)d_in[2];
  const int*  he  = (const int*)d_in[3];
  const void* gW1 = d_in[4];
  const void* gb1 = d_in[5];
  const void* gW2 = d_in[6];
  const void* gb2 = d_in[7];
  const void* hW1 = d_in[8];
  const void* hb1 = d_in[9];
  const void* hW2 = d_in[10];
  const void* hb2 = d_in[11];
  const int*  nit = (const int*)d_in[12];

  float* ws = (float*)d_ws;
  size_t o = 0;
  u16*   xb  = (u16*)(ws + o); o += (size_t)NP*128;
  u16*   BAb = (u16*)(ws + o); o += (size_t)NP*64;
  u16*   BBb = (u16*)(ws + o); o += (size_t)NP*64;
  u16*   BCb = (u16*)(ws + o); o += (size_t)NP*64;
  u16*   BEb = (u16*)(ws + o); o += (size_t)NP*64;
  u16*   BDb = (u16*)(ws + o); o += (size_t)NEH*64;
  u16*  gW1t = (u16*)(ws + o); o += 16384;
  u16*  hW1t = (u16*)(ws + o); o += 16384;
  u16*  gW2t = (u16*)(ws + o); o += 4096;
  u16*  hW2t = (u16*)(ws + o); o += 4096;
  float* gb1f = ws + o; o += 128;
  float* hb1f = ws + o; o += 128;
  float* gb2f = ws + o; o += 64;
  float* hb2f = ws + o; o += 64;
  float* dinv = ws + o; o += 50048;
  float* invv = ws + o; o += 50048;
  float* inve = ws + o; o += 10048;
  float* mu   = ws + o; o += 640;
  float* part = ws + o; o += (size_t)CBLK*640;
  float* pcr  = ws + o; o += CBLK*16;
  float* p2   = ws + o; o += 40*640;
  float* pc2  = ws + o; o += 40*16;
  int*   dflg = (int*)(ws + o); o += 16;
  float* x2f   = (float*)xb;
  float* x4f   = (float*)xb + (size_t)NP*64;
  float* dataf = (float*)BBb;
  // int region (CSR)
  int* ib = (int*)(ws + o);
  size_t io = 0;
  int* cg    = ib + io; io += NN;
  int* cv    = ib + io; io += NN;
  int* ce    = ib + io; io += NEH + 48;
  int* rp_g  = ib + io; io += NN;
  int* rp_v  = ib + io; io += NN;
  int* rp_e  = ib + io; io += NEH + 48;
  int* csr_g = ib + io; io += EE;
  int* csr_e = ib + io; io += NINC;
  int* csr_v = ib + io; io += NINC;
  int* HAg   = ib + io; io += 128*250;
  int* HAv   = ib + io; io += 64*250;
  int* HAe   = ib + io; io += 64*250;
  int* bsg   = ib + io; io += 256;
  int* bsv   = ib + io; io += 256;
  int* bse   = ib + io; io += 256;
  u32* pg = (u32*)(ib + io); io += EE;
  u32* pv = (u32*)(ib + io); io += NINC;
  u32* pe = (u32*)(ib + io); io += NINC;

  const int* srcp = ei;
  const int* dstp = ei + EE;
  dim3 B(256);

  k_detect<<<dim3(1), B, 0, stream>>>((const u16*)x, dflg);
  k_prep<<<dim3(12628), B, 0, stream>>>(x, xb, gW1, hW1, gW2, hW2,
                                        gb1, hb1, gb2, hb2,
                                        gW1t, hW1t, gW2t, hW2t,
                                        gb1f, hb1f, gb2f, hb2f, dflg);

  k_hist_all <<<dim3(256), B, 0, stream>>>(dstp, hv, he, HAg, HAv, HAe);
  k_scanA_all<<<dim3(3),   B, 0, stream>>>(HAg, HAv, HAe, bsg, bsv, bse);
  k_fillA_all<<<dim3(256), B, 0, stream>>>(dstp, srcp, hv, he, HAg, HAv, HAe,
                                           bsg, bsv, bse, pg, pv, pe);
  k_fillB_all<<<dim3(750), B, 0, stream>>>(pg, pv, pe, bsg, bsv, bse,
                                           csr_g, csr_v, csr_e, cg, cv, ce,
                                           rp_g, rp_v, rp_e, dinv, invv, inve);

  k_pA<<<dim3(782),   B, 0, stream>>>(xb, gW1t, dinv, BAb);
  k_pB<<<dim3(13282), B, 0, stream>>>(xb, hW1t, hb1f, BEb,
                                      rp_g, cg, csr_g, dinv, BAb, gb1f, BBb);
  k_pC<<<dim3(3282),  B, 0, stream>>>(BBb, gW2t, dinv, BAb,
                                      rp_e, ce, csr_e, inve, BEb, BDb);
  k_pD<<<dim3(25000), B, 0, stream>>>(rp_v, cv, csr_v, invv, BDb, BCb,
                                      rp_g, cg, csr_g, dinv, BAb, gb2f, x2f);
  k_pE<<<dim3(782),   B, 0, stream>>>(BCb, hW2t, hb2f, BEb);
  k_pF<<<dim3(2500),  B, 0, stream>>>(rp_e, ce, csr_e, inve, BEb, BDb);
  k_pG<<<dim3(12500), B, 0, stream>>>(rp_v, cv, csr_v, invv, BDb, x4f);

  k_embeds<<<dim3((NN+3)/4), B, 0, stream>>>(x2f, x4f, d_out, dataf, dflg);

  k_mu_init<<<dim3(1), dim3(640), 0, stream>>>(dataf, mu);
  for (int it = 0; it < 4; ++it){
    k_cluster_iter<<<dim3(CBLK), dim3(640), 0, stream>>>(dataf, mu, part, pcr, nit, it);
    k_cred1       <<<dim3(40),   dim3(768), 0, stream>>>(part, pcr, p2, pc2, nit, it);
    k_cred2mu     <<<dim3(1),    dim3(768), 0, stream>>>(p2, pc2, mu, nit, it);
  }
  k_cluster_final<<<dim3(CBLK), dim3(640), 0, stream>>>(dataf, mu, d_out, dflg);
}

// Round 18
// 339.543 us; speedup vs baseline: 1.3161x; 1.3161x over previous
//
#include <hip/hip_runtime.h>
#include <hip/hip_bf16.h>

// HGNNP_GCN + ClusterNet forward, MI355X (round 18).
// R17 falsified the src-window theory: FETCH unchanged (95.7MB) at 4x the
// instructions -> per-wave passes cannot create cross-XCD temporal locality;
// gather is L2-miss LATENCY bound (1.7TB/s << L3 ceiling). This round: revert
// to R16 single-pass gathers with the unrolled independent-load group deepened
// 4 -> 8 (8 gathers in flight/wave).

#define NN   50000
#define NP   50048   // padded rows (782 * 64)
#define EE   800000
#define NINC 200000
#define NEH  10000
#define KCL  10
#define CBLK 782     // ceil(NN/64)

#define MU_OFF  0
#define R_OFF   640
#define EMB_OFF 500640
#define D_OFF   3700640

typedef __hip_bfloat16 bf16;
typedef unsigned short u16;
typedef unsigned int   u32;
typedef __attribute__((ext_vector_type(8))) short short8;
typedef __attribute__((ext_vector_type(4))) float f32x4;

__device__ __forceinline__ float b2f(bf16 v){ return __bfloat162float(v); }
__device__ __forceinline__ float us2f(u16 u){ return __uint_as_float(((unsigned)u) << 16); }
__device__ __forceinline__ u16 f2bu(float f){
  unsigned u = __float_as_uint(f);
  return (u16)((u + 0x7fffu + ((u >> 16) & 1u)) >> 16);   // RNE
}
__device__ __forceinline__ bf16 f2b(float f){
  u16 r = f2bu(f);
  bf16 h;
  reinterpret_cast<u16&>(h) = r;
  return h;
}
__device__ __forceinline__ float ldf(const void* p, size_t i, int isbf){
  return isbf ? b2f(((const bf16*)p)[i]) : ((const float*)p)[i];
}
__device__ __forceinline__ void stf(void* p, size_t i, float v, int isbf){
  if (isbf) ((bf16*)p)[i] = f2b(v);
  else      ((float*)p)[i] = v;
}

// ---------------- dtype detector ----------------
__global__ void k_detect(const u16* __restrict__ xr, int* flag){
  __shared__ int bad;
  if (threadIdx.x == 0) bad = 0;
  __syncthreads();
  for (int i = threadIdx.x; i < 4096; i += 256){
    int e = (xr[i] >> 7) & 0xFF;
    if (e >= 0xEF) bad = 1;
  }
  __syncthreads();
  if (threadIdx.x == 0) *flag = bad ? 0 : 1;   // 1 = bf16, 0 = f32
}

// ---------------- fused input prep ----------------
__global__ __launch_bounds__(256) void k_prep(const void* __restrict__ x, u16* __restrict__ xb,
    const void* gW1, const void* hW1, const void* gW2, const void* hW2,
    const void* gb1, const void* hb1, const void* gb2, const void* hb2,
    u16* gW1t, u16* hW1t, u16* gW2t, u16* hW2t,
    float* gb1f, float* hb1f, float* gb2f, float* hb2f,
    const int* __restrict__ flag){
  const int isbf = flag[0];
  const int blk = blockIdx.x;
  if (blk < 12500){
    int i = blk*256 + threadIdx.x;
    ushort4 o;
    if (isbf){
      o = ((const ushort4*)x)[i];
    } else {
      float4 v = ((const float4*)x)[i];
      o = make_ushort4(f2bu(v.x), f2bu(v.y), f2bu(v.z), f2bu(v.w));
    }
    ((ushort4*)xb)[i] = o;
  } else {
    int i = (blk - 12500)*256 + threadIdx.x;
    if (i < 256*128){
      int n = i >> 8, k = i & 255;
      gW1t[i] = f2bu(ldf(gW1, (size_t)k*128 + n, isbf));
      hW1t[i] = f2bu(ldf(hW1, (size_t)k*128 + n, isbf));
    }
    if (i < 64*128){
      int n = i >> 7, k = i & 127;
      gW2t[i] = f2bu(ldf(gW2, (size_t)k*64 + n, isbf));
      hW2t[i] = f2bu(ldf(hW2, (size_t)k*64 + n, isbf));
    }
    if (i < 128){ gb1f[i] = ldf(gb1,i,isbf); hb1f[i] = ldf(hb1,i,isbf); }
    if (i < 64) { gb2f[i] = ldf(gb2,i,isbf); hb2f[i] = ldf(hb2,i,isbf); }
  }
}

// ---------------- fused CSR build ----------------
__global__ __launch_bounds__(256) void k_hist_all(const int* __restrict__ dstp,
    const int* __restrict__ hv, const int* __restrict__ he,
    int* HAg, int* HAv, int* HAe){
  __shared__ u32 hist[250];
  const int blk = blockIdx.x;
  const int* key; int* HA; int chunk, npb, lb;
  if (blk < 128){ key=dstp; HA=HAg; chunk=6250; npb=200; lb=blk; }
  else if (blk < 192){ key=hv; HA=HAv; chunk=3125; npb=200; lb=blk-128; }
  else { key=he; HA=HAe; chunk=3125; npb=40; lb=blk-192; }
  for (int i = threadIdx.x; i < 250; i += 256) hist[i] = 0;
  __syncthreads();
  int base = lb*chunk;
  for (int i = threadIdx.x; i < chunk; i += 256)
    atomicAdd(&hist[key[base+i]/npb], 1u);
  __syncthreads();
  int* out = HA + lb*250;
  for (int i = threadIdx.x; i < 250; i += 256) out[i] = (int)hist[i];
}

__global__ void k_scanA_all(int* HAg, int* HAv, int* HAe,
                            int* bsg, int* bsv, int* bse){
  int* HA; int* bs; int nch;
  if (blockIdx.x == 0){ HA = HAg; bs = bsg; nch = 128; }
  else if (blockIdx.x == 1){ HA = HAv; bs = bsv; nch = 64; }
  else { HA = HAe; bs = bse; nch = 64; }
  __shared__ int s[256];
  int t = threadIdx.x;
  int run = 0;
  if (t < 250){
    for (int c = 0; c < nch; ++c){
      int v = HA[c*250 + t];
      HA[c*250 + t] = run;
      run += v;
    }
  }
  int own = (t < 250) ? run : 0;
  s[t] = own; __syncthreads();
  #pragma unroll
  for (int off = 1; off < 256; off <<= 1){
    int add = (t >= off) ? s[t-off] : 0;
    __syncthreads();
    s[t] += add;
    __syncthreads();
  }
  if (t < 250) bs[t] = s[t] - own;
  if (t == 255) bs[250] = s[255];
}

__global__ __launch_bounds__(256) void k_fillA_all(const int* __restrict__ dstp,
    const int* __restrict__ srcp, const int* __restrict__ hv, const int* __restrict__ he,
    const int* HAg, const int* HAv, const int* HAe,
    const int* bsg, const int* bsv, const int* bse,
    u32* pg, u32* pv, u32* pe){
  __shared__ u32 cur[250];
  const int blk = blockIdx.x;
  const int* key; const int* val; const int* HA; const int* bs; u32* packed;
  int chunk, npb, lb;
  if (blk < 128){ key=dstp; val=srcp; HA=HAg; bs=bsg; packed=pg; chunk=6250; npb=200; lb=blk; }
  else if (blk < 192){ key=hv; val=he; HA=HAv; bs=bsv; packed=pv; chunk=3125; npb=200; lb=blk-128; }
  else { key=he; val=hv; HA=HAe; bs=bse; packed=pe; chunk=3125; npb=40; lb=blk-192; }
  const int* pre = HA + lb*250;
  for (int i = threadIdx.x; i < 250; i += 256) cur[i] = (u32)(bs[i] + pre[i]);
  __syncthreads();
  int base = lb*chunk;
  for (int i = threadIdx.x; i < chunk; i += 256){
    int k = key[base+i];
    int b = k / npb;
    u32 pos = atomicAdd(&cur[b], 1u);
    packed[pos] = ((u32)(k - b*npb) << 16) | (u32)val[base+i];
  }
}

__global__ __launch_bounds__(256) void k_fillB_all(
    const u32* pg, const u32* pv, const u32* pe,
    const int* bsg, const int* bsv, const int* bse,
    int* csr_g, int* csr_v, int* csr_e,
    int* cg, int* cv, int* ce, int* rp_g, int* rp_v, int* rp_e,
    float* dinv, float* invv, float* inve){
  __shared__ u32 hist[200];
  __shared__ int s[256];
  __shared__ u32 cur[200];
  const int blk = blockIdx.x;
  const u32* packed; const int* bs; int* csr; int* cnt; int* rp; int npb, b, mode;
  if (blk < 250){ packed=pg; bs=bsg; csr=csr_g; cnt=cg; rp=rp_g; npb=200; b=blk; mode=0; }
  else if (blk < 500){ packed=pv; bs=bsv; csr=csr_v; cnt=cv; rp=rp_v; npb=200; b=blk-250; mode=1; }
  else { packed=pe; bs=bse; csr=csr_e; cnt=ce; rp=rp_e; npb=40; b=blk-500; mode=2; }
  const int s0 = bs[b], m = bs[b+1] - s0;
  const int t = threadIdx.x;
  for (int i = t; i < npb; i += 256) hist[i] = 0;
  __syncthreads();
  for (int i = t; i < m; i += 256)
    atomicAdd(&hist[packed[s0+i] >> 16], 1u);
  __syncthreads();
  int own = (t < npb) ? (int)hist[t] : 0;
  s[t] = own; __syncthreads();
  #pragma unroll
  for (int off = 1; off < 256; off <<= 1){
    int add = (t >= off) ? s[t-off] : 0;
    __syncthreads();
    s[t] += add;
    __syncthreads();
  }
  if (t < npb){
    int excl = s[t] - own;
    int node = b*npb + t;
    cnt[node] = own;
    rp[node]  = s0 + excl;
    cur[t] = (u32)(s0 + excl);
    if (mode == 0)      dinv[node] = rsqrtf(1.0f + (float)own);
    else if (mode == 1) invv[node] = 1.0f / fmaxf((float)own, 1.0f);
    else                inve[node] = 1.0f / fmaxf((float)own, 1.0f);
  }
  if (mode == 0 && b == 249 && t < NP - NN) dinv[NN + t] = 0.f;  // pad rows
  __syncthreads();
  for (int i = t; i < m; i += 256){
    u32 p = packed[s0+i];
    u32 pos = atomicAdd(&cur[p >> 16], 1u);
    csr[pos] = (int)(p & 0xffffu);
  }
}

// ---------------- MFMA GEMM body ----------------
template<int KDIM, int NCOL>
__device__ __forceinline__ void gemm_body(const u16* __restrict__ A,
    const u16* __restrict__ Wt, const float* __restrict__ bias,
    const float* __restrict__ rowscale, u16* __restrict__ C, int relu, int bid)
{
  constexpr int NT  = NCOL/16;
  constexpr int LDA = 40;
  __shared__ __align__(16) u16 Asl[64][LDA];
  __shared__ __align__(16) u16 Wsl[NCOL][LDA];
  const int tid  = threadIdx.x;
  const int wave = tid >> 6, lane = tid & 63;
  const int l15 = lane & 15, l4 = lane >> 4;
  const int row0 = bid * 64;
  const int ar = tid >> 2, aq = tid & 3;
  constexpr int NW = NCOL*4/256;

  f32x4 acc[NT] = {};

  for (int kk = 0; kk < KDIM; kk += 32){
    {
      uint4 v = *(const uint4*)(A + (size_t)(row0 + ar)*KDIM + kk + aq*8);
      *(uint4*)&Asl[ar][aq*8] = v;
    }
    #pragma unroll
    for (int w2 = 0; w2 < NW; ++w2){
      int c = tid + w2*256;
      int n = c >> 2, q = c & 3;
      uint4 v = *(const uint4*)(Wt + (size_t)n*KDIM + kk + q*8);
      *(uint4*)&Wsl[n][q*8] = v;
    }
    __syncthreads();
    short8 af = *(const short8*)&Asl[wave*16 + l15][l4*8];
    #pragma unroll
    for (int t = 0; t < NT; ++t){
      short8 bf = *(const short8*)&Wsl[t*16 + l15][l4*8];
      acc[t] = __builtin_amdgcn_mfma_f32_16x16x32_bf16(af, bf, acc[t], 0, 0, 0);
    }
    __syncthreads();
  }

  #pragma unroll
  for (int t = 0; t < NT; ++t){
    int gcol = t*16 + l15;
    float b = bias ? bias[gcol] : 0.f;
    #pragma unroll
    for (int e = 0; e < 4; ++e){
      int grow = row0 + wave*16 + l4*4 + e;
      float v = acc[t][e] + b;
      if (relu) v = fmaxf(v, 0.f);
      if (rowscale) v *= rowscale[grow];
      C[(size_t)grow*NCOL + gcol] = f2bu(v);
    }
  }
}

// ---------------- gather body: wave/row, 8-deep independent loads ----------------
template<int F, bool OUTBF, bool SELF>
__device__ __forceinline__ void gather_body(const int* __restrict__ rp,
    const int* __restrict__ cnt, const int* __restrict__ csr,
    const float* __restrict__ scale, const u16* __restrict__ h,
    const float* __restrict__ bias, void* __restrict__ out, int relu, int bid)
{
  const int wave = threadIdx.x >> 6, lane = threadIdx.x & 63;
  const int d = bid*4 + wave;
  const int k0 = rp[d], n = cnt[d];

  if constexpr (F == 128){
    const uint* h32 = (const uint*)h;
    float a0=0,a1=0,b0=0,b1=0,c0=0,c1=0,d0=0,d1=0;
    float e0=0,e1=0,f0=0,f1=0,g0=0,g1=0,h0=0,h1=0;
    if (SELF){
      uint v = h32[(size_t)d*64 + lane];
      a0 = us2f((u16)v); a1 = us2f((u16)(v>>16));
    }
    for (int base = 0; base < n; base += 64){
      int mm = n - base; if (mm > 64) mm = 64;
      int idx = (lane < mm) ? csr[k0 + base + lane] : 0;
      int jj = 0;
      for (; jj + 8 <= mm; jj += 8){
        int s0=__shfl(idx,jj),   s1=__shfl(idx,jj+1), s2=__shfl(idx,jj+2), s3=__shfl(idx,jj+3);
        int s4=__shfl(idx,jj+4), s5=__shfl(idx,jj+5), s6=__shfl(idx,jj+6), s7=__shfl(idx,jj+7);
        uint v0 = h32[(size_t)s0*64 + lane];
        uint v1 = h32[(size_t)s1*64 + lane];
        uint v2 = h32[(size_t)s2*64 + lane];
        uint v3 = h32[(size_t)s3*64 + lane];
        uint v4 = h32[(size_t)s4*64 + lane];
        uint v5 = h32[(size_t)s5*64 + lane];
        uint v6 = h32[(size_t)s6*64 + lane];
        uint v7 = h32[(size_t)s7*64 + lane];
        a0 += us2f((u16)v0); a1 += us2f((u16)(v0>>16));
        b0 += us2f((u16)v1); b1 += us2f((u16)(v1>>16));
        c0 += us2f((u16)v2); c1 += us2f((u16)(v2>>16));
        d0 += us2f((u16)v3); d1 += us2f((u16)(v3>>16));
        e0 += us2f((u16)v4); e1 += us2f((u16)(v4>>16));
        f0 += us2f((u16)v5); f1 += us2f((u16)(v5>>16));
        g0 += us2f((u16)v6); g1 += us2f((u16)(v6>>16));
        h0 += us2f((u16)v7); h1 += us2f((u16)(v7>>16));
      }
      for (; jj < mm; ++jj){
        int s = __shfl(idx, jj);
        uint v = h32[(size_t)s*64 + lane];
        a0 += us2f((u16)v); a1 += us2f((u16)(v>>16));
      }
    }
    float sc = scale[d];
    float o0 = (((a0+b0)+(c0+d0)) + ((e0+f0)+(g0+h0)))*sc;
    float o1 = (((a1+b1)+(c1+d1)) + ((e1+f1)+(g1+h1)))*sc;
    if (bias){ o0 += bias[lane*2]; o1 += bias[lane*2+1]; }
    if (relu){ o0 = fmaxf(o0,0.f); o1 = fmaxf(o1,0.f); }
    if (OUTBF){
      ((uint*)out)[(size_t)d*64 + lane] = (uint)f2bu(o0) | ((uint)f2bu(o1) << 16);
    } else {
      ((float2*)out)[(size_t)d*64 + lane] = make_float2(o0, o1);
    }
  } else { // F == 64
    float a=0,b=0,c=0,dd2=0,e=0,f=0,g=0,hh=0;
    if (SELF) a = us2f(h[(size_t)d*64 + lane]);
    for (int base = 0; base < n; base += 64){
      int mm = n - base; if (mm > 64) mm = 64;
      int idx = (lane < mm) ? csr[k0 + base + lane] : 0;
      int jj = 0;
      for (; jj + 8 <= mm; jj += 8){
        int s0=__shfl(idx,jj),   s1=__shfl(idx,jj+1), s2=__shfl(idx,jj+2), s3=__shfl(idx,jj+3);
        int s4=__shfl(idx,jj+4), s5=__shfl(idx,jj+5), s6=__shfl(idx,jj+6), s7=__shfl(idx,jj+7);
        a   += us2f(h[(size_t)s0*64 + lane]);
        b   += us2f(h[(size_t)s1*64 + lane]);
        c   += us2f(h[(size_t)s2*64 + lane]);
        dd2 += us2f(h[(size_t)s3*64 + lane]);
        e   += us2f(h[(size_t)s4*64 + lane]);
        f   += us2f(h[(size_t)s5*64 + lane]);
        g   += us2f(h[(size_t)s6*64 + lane]);
        hh  += us2f(h[(size_t)s7*64 + lane]);
      }
      for (; jj < mm; ++jj){
        int s = __shfl(idx, jj);
        a += us2f(h[(size_t)s*64 + lane]);
      }
    }
    float o = (((a+b)+(c+dd2)) + ((e+f)+(g+hh)))*scale[d];
    if (bias) o += bias[lane];
    if (relu) o = fmaxf(o, 0.f);
    if (OUTBF) ((u16*)out)[(size_t)d*64 + lane] = f2bu(o);
    else       ((float*)out)[(size_t)d*64 + lane] = o;
  }
}

// ---------------- phase kernels ----------------
__global__ __launch_bounds__(256) void k_pA(const u16* xb, const u16* gW1t,
    const float* dinv, u16* BAb){
  gemm_body<256,128>(xb, gW1t, nullptr, dinv, BAb, 0, blockIdx.x);
}
__global__ __launch_bounds__(256) void k_pB(const u16* xb, const u16* hW1t,
    const float* hb1f, u16* BEb,
    const int* rp_g, const int* cg, const int* csr_g, const float* dinv,
    const u16* BAb, const float* gb1f, u16* BBb){
  if (blockIdx.x < 782) gemm_body<256,128>(xb, hW1t, hb1f, nullptr, BEb, 0, blockIdx.x);
  else gather_body<128,true,true>(rp_g, cg, csr_g, dinv, BAb, gb1f, BBb, 1, blockIdx.x - 782);
}
__global__ __launch_bounds__(256) void k_pC(const u16* BBb, const u16* gW2t,
    const float* dinv, u16* BAb,
    const int* rp_e, const int* ce, const int* csr_e, const float* inve,
    const u16* BEb, u16* BDb){
  if (blockIdx.x < 782) gemm_body<128,64>(BBb, gW2t, nullptr, dinv, BAb, 0, blockIdx.x);
  else gather_body<128,true,false>(rp_e, ce, csr_e, inve, BEb, nullptr, BDb, 0, blockIdx.x - 782);
}
__global__ __launch_bounds__(256) void k_pD(
    const int* rp_v, const int* cv, const int* csr_v, const float* invv,
    const u16* BDb, u16* BCb,
    const int* rp_g, const int* cg, const int* csr_g, const float* dinv,
    const u16* BAb, const float* gb2f, float* x2f){
  if (blockIdx.x < 12500) gather_body<128,true,false>(rp_v, cv, csr_v, invv, BDb, nullptr, BCb, 1, blockIdx.x);
  else gather_body<64,false,true>(rp_g, cg, csr_g, dinv, BAb, gb2f, x2f, 0, blockIdx.x - 12500);
}
__global__ __launch_bounds__(256) void k_pE(const u16* BCb, const u16* hW2t,
    const float* hb2f, u16* BEb){
  gemm_body<128,64>(BCb, hW2t, hb2f, nullptr, BEb, 0, blockIdx.x);
}
__global__ __launch_bounds__(256) void k_pF(const int* rp_e, const int* ce,
    const int* csr_e, const float* inve, const u16* BEb, u16* BDb){
  gather_body<64,true,false>(rp_e, ce, csr_e, inve, BEb, nullptr, BDb, 0, blockIdx.x);
}
__global__ __launch_bounds__(256) void k_pG(const int* rp_v, const int* cv,
    const int* csr_v, const float* invv, const u16* BDb, float* x4f){
  gather_body<64,false,false>(rp_v, cv, csr_v, invv, BDb, nullptr, x4f, 0, blockIdx.x);
}

// ---------------- embeds + row normalize ----------------
__global__ void k_embeds(const float* __restrict__ x2, const float* __restrict__ x4,
                         void* __restrict__ out, float* __restrict__ data,
                         const int* __restrict__ flag){
  int row  = blockIdx.x*4 + (threadIdx.x >> 6);
  int lane = threadIdx.x & 63;
  if (row >= NN) return;
  size_t idx = (size_t)row*64 + lane;
  float v = 0.5f*(x2[idx] + x4[idx]);
  float ss = v*v;
  #pragma unroll
  for (int off=32; off>0; off>>=1) ss += __shfl_xor(ss, off);
  float inv = rsqrtf(ss);
  data[idx] = v*inv;
  stf(out, EMB_OFF + idx, v, flag[0]);
}

// ---------------- clustering ----------------
__global__ void k_mu_init(const float* __restrict__ data, float* __restrict__ mu){
  int p = threadIdx.x;      // 640 threads, 1 block
  int k = p >> 6, f = p & 63;
  mu[p] = data[(size_t)k*(NN/KCL)*64 + f];
}

__global__ __launch_bounds__(640) void k_cluster_iter(const float* __restrict__ data,
    const float* __restrict__ mu, float* __restrict__ part, float* __restrict__ pcr,
    const int* __restrict__ nit, int iter)
{
  if (iter >= nit[0]) return;
  __shared__ float ms[640];
  __shared__ float dt[64][65];
  __shared__ float ds[64][11];
  const int tid = threadIdx.x;
  ms[tid] = mu[tid];
  const int base = blockIdx.x*64;
  for (int i = tid; i < 4096; i += 640){
    int r = i >> 6, f = i & 63;
    int grow = base + r;
    dt[r][f] = (grow < NN) ? data[(size_t)grow*64 + f] : 0.f;
  }
  __syncthreads();
  {
    const int row = tid & 63, k = tid >> 6;
    float dot = 0.f;
    #pragma unroll 16
    for (int f = 0; f < 64; ++f)
      dot = fmaf(dt[row][f], ms[k*64 + f], dot);
    ds[row][k] = dot;
  }
  __syncthreads();
  if (tid < 64){
    float dot[KCL];
    #pragma unroll
    for (int k = 0; k < KCL; ++k) dot[k] = ds[tid][k];
    float m = -1e30f;
    #pragma unroll
    for (int k = 0; k < KCL; ++k) m = fmaxf(m, 5.0f*dot[k]);
    float s = 0.f, ev[KCL];
    #pragma unroll
    for (int k = 0; k < KCL; ++k){ ev[k] = expf(5.0f*dot[k]-m); s += ev[k]; }
    float inv = (base + tid < NN) ? 1.0f/s : 0.f;
    #pragma unroll
    for (int k = 0; k < KCL; ++k) ds[tid][k] = ev[k]*inv;
  }
  __syncthreads();
  {
    const int f = tid & 63, k = tid >> 6;
    float acc = 0.f, crp = 0.f;
    #pragma unroll 8
    for (int t = 0; t < 64; ++t){
      float rv = ds[t][k];
      acc = fmaf(rv, dt[t][f], acc);
      crp += rv;
    }
    part[(size_t)blockIdx.x*640 + tid] = acc;
    if (f == 0) pcr[blockIdx.x*16 + k] = crp;
  }
}

__global__ void k_cred1(const float* __restrict__ part, const float* __restrict__ pcr,
                        float* __restrict__ p2, float* __restrict__ pc2,
                        const int* __restrict__ nit, int iter){
  if (iter >= nit[0]) return;
  int b = blockIdx.x, t = threadIdx.x;
  int r0 = b*20, r1 = r0 + 20; if (r1 > CBLK) r1 = CBLK;
  if (t < 640){
    float a = 0.f;
    for (int r = r0; r < r1; ++r) a += part[(size_t)r*640 + t];
    p2[(size_t)b*640 + t] = a;
  } else if (t < 640 + KCL){
    int k = t - 640;
    float a = 0.f;
    for (int r = r0; r < r1; ++r) a += pcr[r*16 + k];
    pc2[b*16 + k] = a;
  }
}

__global__ void k_cred2mu(const float* __restrict__ p2, const float* __restrict__ pc2,
                          float* __restrict__ mu, const int* __restrict__ nit, int iter){
  if (iter >= nit[0]) return;
  __shared__ float crs[16];
  int t = threadIdx.x;
  if (t >= 640 && t < 640 + KCL){
    int k = t - 640;
    float a = 0.f;
    #pragma unroll
    for (int b = 0; b < 40; ++b) a += pc2[b*16 + k];
    crs[k] = a;
  }
  __syncthreads();
  if (t < 640){
    float a = 0.f;
    #pragma unroll
    for (int b = 0; b < 40; ++b) a += p2[(size_t)b*640 + t];
    mu[t] = a / crs[t >> 6];
  }
}

__global__ __launch_bounds__(640) void k_cluster_final(const float* __restrict__ data,
    const float* __restrict__ mu, void* __restrict__ out, const int* __restrict__ flag)
{
  __shared__ float ms[640];
  __shared__ float dt[64][65];
  __shared__ float ds[64][11];
  const int tid = threadIdx.x;
  ms[tid] = mu[tid];
  const int base = blockIdx.x*64;
  for (int i = tid; i < 4096; i += 640){
    int r = i >> 6, f = i & 63;
    int grow = base + r;
    dt[r][f] = (grow < NN) ? data[(size_t)grow*64 + f] : 0.f;
  }
  __syncthreads();
  {
    const int row = tid & 63, k = tid >> 6;
    float dot = 0.f;
    #pragma unroll 16
    for (int f = 0; f < 64; ++f)
      dot = fmaf(dt[row][f], ms[k*64 + f], dot);
    ds[row][k] = dot;
  }
  __syncthreads();
  const int isbf = flag[0];
  if (blockIdx.x == 0) stf(out, MU_OFF + tid, ms[tid], isbf);
  if (tid < 64 && base + tid < NN){
    const int row = base + tid;
    float dot[KCL];
    #pragma unroll
    for (int k = 0; k < KCL; ++k) dot[k] = ds[tid][k];
    float m = -1e30f;
    #pragma unroll
    for (int k = 0; k < KCL; ++k) m = fmaxf(m, 5.0f*dot[k]);
    float s = 0.f, ev[KCL];
    #pragma unroll
    for (int k = 0; k < KCL; ++k){ ev[k] = expf(5.0f*dot[k]-m); s += ev[k]; }
    float inv = 1.0f/s;
    #pragma unroll
    for (int k = 0; k < KCL; ++k){
      stf(out, (size_t)D_OFF + (size_t)row*KCL + k, dot[k],    isbf);
      stf(out, (size_t)R_OFF + (size_t)row*KCL + k, ev[k]*inv, isbf);
    }
  }
}

// ---------------- launch ----------------
extern "C" void kernel_launch(void* const* d_in, const int* in_sizes, int n_in,
                              void* d_out, int out_size, void* d_ws, size_t ws_size,
                              hipStream_t stream)
{
  const void* x   = d_in[0];
  const int*  ei  = (const int*)d_in[1];
  const int*  hv  = (const int*)d_in[2];
  const int*  he  = (const int*)d_in[3];
  const void* gW1 = d_in[4];
  const void* gb1 = d_in[5];
  const void* gW2 = d_in[6];
  const void* gb2 = d_in[7];
  const void* hW1 = d_in[8];
  const void* hb1 = d_in[9];
  const void* hW2 = d_in[10];
  const void* hb2 = d_in[11];
  const int*  nit = (const int*)d_in[12];

  float* ws = (float*)d_ws;
  size_t o = 0;
  u16*   xb  = (u16*)(ws + o); o += (size_t)NP*128;
  u16*   BAb = (u16*)(ws + o); o += (size_t)NP*64;
  u16*   BBb = (u16*)(ws + o); o += (size_t)NP*64;
  u16*   BCb = (u16*)(ws + o); o += (size_t)NP*64;
  u16*   BEb = (u16*)(ws + o); o += (size_t)NP*64;
  u16*   BDb = (u16*)(ws + o); o += (size_t)NEH*64;
  u16*  gW1t = (u16*)(ws + o); o += 16384;
  u16*  hW1t = (u16*)(ws + o); o += 16384;
  u16*  gW2t = (u16*)(ws + o); o += 4096;
  u16*  hW2t = (u16*)(ws + o); o += 4096;
  float* gb1f = ws + o; o += 128;
  float* hb1f = ws + o; o += 128;
  float* gb2f = ws + o; o += 64;
  float* hb2f = ws + o; o += 64;
  float* dinv = ws + o; o += 50048;
  float* invv = ws + o; o += 50048;
  float* inve = ws + o; o += 10048;
  float* mu   = ws + o; o += 640;
  float* part = ws + o; o += (size_t)CBLK*640;
  float* pcr  = ws + o; o += CBLK*16;
  float* p2   = ws + o; o += 40*640;
  float* pc2  = ws + o; o += 40*16;
  int*   dflg = (int*)(ws + o); o += 16;
  float* x2f   = (float*)xb;
  float* x4f   = (float*)xb + (size_t)NP*64;
  float* dataf = (float*)BBb;
  // int region (CSR)
  int* ib = (int*)(ws + o);
  size_t io = 0;
  int* cg    = ib + io; io += NN;
  int* cv    = ib + io; io += NN;
  int* ce    = ib + io; io += NEH + 48;
  int* rp_g  = ib + io; io += NN;
  int* rp_v  = ib + io; io += NN;
  int* rp_e  = ib + io; io += NEH + 48;
  int* csr_g = ib + io; io += EE;
  int* csr_e = ib + io; io += NINC;
  int* csr_v = ib + io; io += NINC;
  int* HAg   = ib + io; io += 128*250;
  int* HAv   = ib + io; io += 64*250;
  int* HAe   = ib + io; io += 64*250;
  int* bsg   = ib + io; io += 256;
  int* bsv   = ib + io; io += 256;
  int* bse   = ib + io; io += 256;
  u32* pg = (u32*)(ib + io); io += EE;
  u32* pv = (u32*)(ib + io); io += NINC;
  u32* pe = (u32*)(ib + io); io += NINC;

  const int* srcp = ei;
  const int* dstp = ei + EE;
  dim3 B(256);

  k_detect<<<dim3(1), B, 0, stream>>>((const u16*)x, dflg);
  k_prep<<<dim3(12628), B, 0, stream>>>(x, xb, gW1, hW1, gW2, hW2,
                                        gb1, hb1, gb2, hb2,
                                        gW1t, hW1t, gW2t, hW2t,
                                        gb1f, hb1f, gb2f, hb2f, dflg);

  k_hist_all <<<dim3(256), B, 0, stream>>>(dstp, hv, he, HAg, HAv, HAe);
  k_scanA_all<<<dim3(3),   B, 0, stream>>>(HAg, HAv, HAe, bsg, bsv, bse);
  k_fillA_all<<<dim3(256), B, 0, stream>>>(dstp, srcp, hv, he, HAg, HAv, HAe,
                                           bsg, bsv, bse, pg, pv, pe);
  k_fillB_all<<<dim3(750), B, 0, stream>>>(pg, pv, pe, bsg, bsv, bse,
                                           csr_g, csr_v, csr_e, cg, cv, ce,
                                           rp_g, rp_v, rp_e, dinv, invv, inve);

  k_pA<<<dim3(782),   B, 0, stream>>>(xb, gW1t, dinv, BAb);
  k_pB<<<dim3(13282), B, 0, stream>>>(xb, hW1t, hb1f, BEb,
                                      rp_g, cg, csr_g, dinv, BAb, gb1f, BBb);
  k_pC<<<dim3(3282),  B, 0, stream>>>(BBb, gW2t, dinv, BAb,
                                      rp_e, ce, csr_e, inve, BEb, BDb);
  k_pD<<<dim3(25000), B, 0, stream>>>(rp_v, cv, csr_v, invv, BDb, BCb,
                                      rp_g, cg, csr_g, dinv, BAb, gb2f, x2f);
  k_pE<<<dim3(782),   B, 0, stream>>>(BCb, hW2t, hb2f, BEb);
  k_pF<<<dim3(2500),  B, 0, stream>>>(rp_e, ce, csr_e, inve, BEb, BDb);
  k_pG<<<dim3(12500), B, 0, stream>>>(rp_v, cv, csr_v, invv, BDb, x4f);

  k_embeds<<<dim3((NN+3)/4), B, 0, stream>>>(x2f, x4f, d_out, dataf, dflg);

  k_mu_init<<<dim3(1), dim3(640), 0, stream>>>(dataf, mu);
  for (int it = 0; it < 4; ++it){
    k_cluster_iter<<<dim3(CBLK), dim3(640), 0, stream>>>(dataf, mu, part, pcr, nit, it);
    k_cred1       <<<dim3(40),   dim3(768), 0, stream>>>(part, pcr, p2, pc2, nit, it);
    k_cred2mu     <<<dim3(1),    dim3(768), 0, stream>>>(p2, pc2, mu, nit, it);
  }
  k_cluster_final<<<dim3(CBLK), dim3(640), 0, stream>>>(dataf, mu, d_out, dflg);
}

// Round 21
// 313.982 us; speedup vs baseline: 1.4232x; 1.0814x over previous
//
#include <hip/hip_runtime.h>
#include <hip/hip_bf16.h>

// HGNNP_GCN + ClusterNet forward, MI355X (round 21 = round 19 resubmit; two
// consecutive infra failures on the same pod, source never executed).
// R17/R18 falsified both gather theories: FETCH pinned at ~96MB (= per-XCD
// compulsory 12.8MB x 8 XCDs) across windowed/4-deep/8-deep variants; 8-deep
// cost occupancy (44->35%) and slowed down. Gather is at the ~2TB/s random
// L3 service floor. This round: revert to the proven R16 4-deep gather and
// fuse embeds into the v2-gather epilogue (same wave-per-row layout).

#define NN   50000
#define NP   50048   // padded rows (782 * 64)
#define EE   800000
#define NINC 200000
#define NEH  10000
#define KCL  10
#define CBLK 782     // ceil(NN/64)

#define MU_OFF  0
#define R_OFF   640
#define EMB_OFF 500640
#define D_OFF   3700640

typedef __hip_bfloat16 bf16;
typedef unsigned short u16;
typedef unsigned int   u32;
typedef __attribute__((ext_vector_type(8))) short short8;
typedef __attribute__((ext_vector_type(4))) float f32x4;

__device__ __forceinline__ float b2f(bf16 v){ return __bfloat162float(v); }
__device__ __forceinline__ float us2f(u16 u){ return __uint_as_float(((unsigned)u) << 16); }
__device__ __forceinline__ u16 f2bu(float f){
  unsigned u = __float_as_uint(f);
  return (u16)((u + 0x7fffu + ((u >> 16) & 1u)) >> 16);   // RNE
}
__device__ __forceinline__ bf16 f2b(float f){
  u16 r = f2bu(f);
  bf16 h;
  reinterpret_cast<u16&>(h) = r;
  return h;
}
__device__ __forceinline__ float ldf(const void* p, size_t i, int isbf){
  return isbf ? b2f(((const bf16*)p)[i]) : ((const float*)p)[i];
}
__device__ __forceinline__ void stf(void* p, size_t i, float v, int isbf){
  if (isbf) ((bf16*)p)[i] = f2b(v);
  else      ((float*)p)[i] = v;
}

// ---------------- dtype detector ----------------
__global__ void k_detect(const u16* __restrict__ xr, int* flag){
  __shared__ int bad;
  if (threadIdx.x == 0) bad = 0;
  __syncthreads();
  for (int i = threadIdx.x; i < 4096; i += 256){
    int e = (xr[i] >> 7) & 0xFF;
    if (e >= 0xEF) bad = 1;
  }
  __syncthreads();
  if (threadIdx.x == 0) *flag = bad ? 0 : 1;   // 1 = bf16, 0 = f32
}

// ---------------- fused input prep ----------------
__global__ __launch_bounds__(256) void k_prep(const void* __restrict__ x, u16* __restrict__ xb,
    const void* gW1, const void* hW1, const void* gW2, const void* hW2,
    const void* gb1, const void* hb1, const void* gb2, const void* hb2,
    u16* gW1t, u16* hW1t, u16* gW2t, u16* hW2t,
    float* gb1f, float* hb1f, float* gb2f, float* hb2f,
    const int* __restrict__ flag){
  const int isbf = flag[0];
  const int blk = blockIdx.x;
  if (blk < 12500){
    int i = blk*256 + threadIdx.x;
    ushort4 o;
    if (isbf){
      o = ((const ushort4*)x)[i];
    } else {
      float4 v = ((const float4*)x)[i];
      o = make_ushort4(f2bu(v.x), f2bu(v.y), f2bu(v.z), f2bu(v.w));
    }
    ((ushort4*)xb)[i] = o;
  } else {
    int i = (blk - 12500)*256 + threadIdx.x;
    if (i < 256*128){
      int n = i >> 8, k = i & 255;
      gW1t[i] = f2bu(ldf(gW1, (size_t)k*128 + n, isbf));
      hW1t[i] = f2bu(ldf(hW1, (size_t)k*128 + n, isbf));
    }
    if (i < 64*128){
      int n = i >> 7, k = i & 127;
      gW2t[i] = f2bu(ldf(gW2, (size_t)k*64 + n, isbf));
      hW2t[i] = f2bu(ldf(hW2, (size_t)k*64 + n, isbf));
    }
    if (i < 128){ gb1f[i] = ldf(gb1,i,isbf); hb1f[i] = ldf(hb1,i,isbf); }
    if (i < 64) { gb2f[i] = ldf(gb2,i,isbf); hb2f[i] = ldf(hb2,i,isbf); }
  }
}

// ---------------- fused CSR build ----------------
__global__ __launch_bounds__(256) void k_hist_all(const int* __restrict__ dstp,
    const int* __restrict__ hv, const int* __restrict__ he,
    int* HAg, int* HAv, int* HAe){
  __shared__ u32 hist[250];
  const int blk = blockIdx.x;
  const int* key; int* HA; int chunk, npb, lb;
  if (blk < 128){ key=dstp; HA=HAg; chunk=6250; npb=200; lb=blk; }
  else if (blk < 192){ key=hv; HA=HAv; chunk=3125; npb=200; lb=blk-128; }
  else { key=he; HA=HAe; chunk=3125; npb=40; lb=blk-192; }
  for (int i = threadIdx.x; i < 250; i += 256) hist[i] = 0;
  __syncthreads();
  int base = lb*chunk;
  for (int i = threadIdx.x; i < chunk; i += 256)
    atomicAdd(&hist[key[base+i]/npb], 1u);
  __syncthreads();
  int* out = HA + lb*250;
  for (int i = threadIdx.x; i < 250; i += 256) out[i] = (int)hist[i];
}

__global__ void k_scanA_all(int* HAg, int* HAv, int* HAe,
                            int* bsg, int* bsv, int* bse){
  int* HA; int* bs; int nch;
  if (blockIdx.x == 0){ HA = HAg; bs = bsg; nch = 128; }
  else if (blockIdx.x == 1){ HA = HAv; bs = bsv; nch = 64; }
  else { HA = HAe; bs = bse; nch = 64; }
  __shared__ int s[256];
  int t = threadIdx.x;
  int run = 0;
  if (t < 250){
    for (int c = 0; c < nch; ++c){
      int v = HA[c*250 + t];
      HA[c*250 + t] = run;
      run += v;
    }
  }
  int own = (t < 250) ? run : 0;
  s[t] = own; __syncthreads();
  #pragma unroll
  for (int off = 1; off < 256; off <<= 1){
    int add = (t >= off) ? s[t-off] : 0;
    __syncthreads();
    s[t] += add;
    __syncthreads();
  }
  if (t < 250) bs[t] = s[t] - own;
  if (t == 255) bs[250] = s[255];
}

__global__ __launch_bounds__(256) void k_fillA_all(const int* __restrict__ dstp,
    const int* __restrict__ srcp, const int* __restrict__ hv, const int* __restrict__ he,
    const int* HAg, const int* HAv, const int* HAe,
    const int* bsg, const int* bsv, const int* bse,
    u32* pg, u32* pv, u32* pe){
  __shared__ u32 cur[250];
  const int blk = blockIdx.x;
  const int* key; const int* val; const int* HA; const int* bs; u32* packed;
  int chunk, npb, lb;
  if (blk < 128){ key=dstp; val=srcp; HA=HAg; bs=bsg; packed=pg; chunk=6250; npb=200; lb=blk; }
  else if (blk < 192){ key=hv; val=he; HA=HAv; bs=bsv; packed=pv; chunk=3125; npb=200; lb=blk-128; }
  else { key=he; val=hv; HA=HAe; bs=bse; packed=pe; chunk=3125; npb=40; lb=blk-192; }
  const int* pre = HA + lb*250;
  for (int i = threadIdx.x; i < 250; i += 256) cur[i] = (u32)(bs[i] + pre[i]);
  __syncthreads();
  int base = lb*chunk;
  for (int i = threadIdx.x; i < chunk; i += 256){
    int k = key[base+i];
    int b = k / npb;
    u32 pos = atomicAdd(&cur[b], 1u);
    packed[pos] = ((u32)(k - b*npb) << 16) | (u32)val[base+i];
  }
}

__global__ __launch_bounds__(256) void k_fillB_all(
    const u32* pg, const u32* pv, const u32* pe,
    const int* bsg, const int* bsv, const int* bse,
    int* csr_g, int* csr_v, int* csr_e,
    int* cg, int* cv, int* ce, int* rp_g, int* rp_v, int* rp_e,
    float* dinv, float* invv, float* inve){
  __shared__ u32 hist[200];
  __shared__ int s[256];
  __shared__ u32 cur[200];
  const int blk = blockIdx.x;
  const u32* packed; const int* bs; int* csr; int* cnt; int* rp; int npb, b, mode;
  if (blk < 250){ packed=pg; bs=bsg; csr=csr_g; cnt=cg; rp=rp_g; npb=200; b=blk; mode=0; }
  else if (blk < 500){ packed=pv; bs=bsv; csr=csr_v; cnt=cv; rp=rp_v; npb=200; b=blk-250; mode=1; }
  else { packed=pe; bs=bse; csr=csr_e; cnt=ce; rp=rp_e; npb=40; b=blk-500; mode=2; }
  const int s0 = bs[b], m = bs[b+1] - s0;
  const int t = threadIdx.x;
  for (int i = t; i < npb; i += 256) hist[i] = 0;
  __syncthreads();
  for (int i = t; i < m; i += 256)
    atomicAdd(&hist[packed[s0+i] >> 16], 1u);
  __syncthreads();
  int own = (t < npb) ? (int)hist[t] : 0;
  s[t] = own; __syncthreads();
  #pragma unroll
  for (int off = 1; off < 256; off <<= 1){
    int add = (t >= off) ? s[t-off] : 0;
    __syncthreads();
    s[t] += add;
    __syncthreads();
  }
  if (t < npb){
    int excl = s[t] - own;
    int node = b*npb + t;
    cnt[node] = own;
    rp[node]  = s0 + excl;
    cur[t] = (u32)(s0 + excl);
    if (mode == 0)      dinv[node] = rsqrtf(1.0f + (float)own);
    else if (mode == 1) invv[node] = 1.0f / fmaxf((float)own, 1.0f);
    else                inve[node] = 1.0f / fmaxf((float)own, 1.0f);
  }
  if (mode == 0 && b == 249 && t < NP - NN) dinv[NN + t] = 0.f;  // pad rows
  __syncthreads();
  for (int i = t; i < m; i += 256){
    u32 p = packed[s0+i];
    u32 pos = atomicAdd(&cur[p >> 16], 1u);
    csr[pos] = (int)(p & 0xffffu);
  }
}

// ---------------- MFMA GEMM body ----------------
template<int KDIM, int NCOL>
__device__ __forceinline__ void gemm_body(const u16* __restrict__ A,
    const u16* __restrict__ Wt, const float* __restrict__ bias,
    const float* __restrict__ rowscale, u16* __restrict__ C, int relu, int bid)
{
  constexpr int NT  = NCOL/16;
  constexpr int LDA = 40;
  __shared__ __align__(16) u16 Asl[64][LDA];
  __shared__ __align__(16) u16 Wsl[NCOL][LDA];
  const int tid  = threadIdx.x;
  const int wave = tid >> 6, lane = tid & 63;
  const int l15 = lane & 15, l4 = lane >> 4;
  const int row0 = bid * 64;
  const int ar = tid >> 2, aq = tid & 3;
  constexpr int NW = NCOL*4/256;

  f32x4 acc[NT] = {};

  for (int kk = 0; kk < KDIM; kk += 32){
    {
      uint4 v = *(const uint4*)(A + (size_t)(row0 + ar)*KDIM + kk + aq*8);
      *(uint4*)&Asl[ar][aq*8] = v;
    }
    #pragma unroll
    for (int w2 = 0; w2 < NW; ++w2){
      int c = tid + w2*256;
      int n = c >> 2, q = c & 3;
      uint4 v = *(const uint4*)(Wt + (size_t)n*KDIM + kk + q*8);
      *(uint4*)&Wsl[n][q*8] = v;
    }
    __syncthreads();
    short8 af = *(const short8*)&Asl[wave*16 + l15][l4*8];
    #pragma unroll
    for (int t = 0; t < NT; ++t){
      short8 bf = *(const short8*)&Wsl[t*16 + l15][l4*8];
      acc[t] = __builtin_amdgcn_mfma_f32_16x16x32_bf16(af, bf, acc[t], 0, 0, 0);
    }
    __syncthreads();
  }

  #pragma unroll
  for (int t = 0; t < NT; ++t){
    int gcol = t*16 + l15;
    float b = bias ? bias[gcol] : 0.f;
    #pragma unroll
    for (int e = 0; e < 4; ++e){
      int grow = row0 + wave*16 + l4*4 + e;
      float v = acc[t][e] + b;
      if (relu) v = fmaxf(v, 0.f);
      if (rowscale) v *= rowscale[grow];
      C[(size_t)grow*NCOL + gcol] = f2bu(v);
    }
  }
}

// ---------------- gather body: wave/row, 4-deep independent loads (R16) ----------------
template<int F, bool OUTBF, bool SELF>
__device__ __forceinline__ void gather_body(const int* __restrict__ rp,
    const int* __restrict__ cnt, const int* __restrict__ csr,
    const float* __restrict__ scale, const u16* __restrict__ h,
    const float* __restrict__ bias, void* __restrict__ out, int relu, int bid)
{
  const int wave = threadIdx.x >> 6, lane = threadIdx.x & 63;
  const int d = bid*4 + wave;
  const int k0 = rp[d], n = cnt[d];

  if constexpr (F == 128){
    const uint* h32 = (const uint*)h;
    float a0=0,a1=0,b0=0,b1=0,c0=0,c1=0,e0=0,e1=0;
    if (SELF){
      uint v = h32[(size_t)d*64 + lane];
      a0 = us2f((u16)v); a1 = us2f((u16)(v>>16));
    }
    for (int base = 0; base < n; base += 64){
      int mm = n - base; if (mm > 64) mm = 64;
      int idx = (lane < mm) ? csr[k0 + base + lane] : 0;
      int jj = 0;
      for (; jj + 4 <= mm; jj += 4){
        int s0=__shfl(idx,jj), s1=__shfl(idx,jj+1), s2=__shfl(idx,jj+2), s3=__shfl(idx,jj+3);
        uint v0 = h32[(size_t)s0*64 + lane];
        uint v1 = h32[(size_t)s1*64 + lane];
        uint v2 = h32[(size_t)s2*64 + lane];
        uint v3 = h32[(size_t)s3*64 + lane];
        a0 += us2f((u16)v0); a1 += us2f((u16)(v0>>16));
        b0 += us2f((u16)v1); b1 += us2f((u16)(v1>>16));
        c0 += us2f((u16)v2); c1 += us2f((u16)(v2>>16));
        e0 += us2f((u16)v3); e1 += us2f((u16)(v3>>16));
      }
      for (; jj < mm; ++jj){
        int s = __shfl(idx, jj);
        uint v = h32[(size_t)s*64 + lane];
        a0 += us2f((u16)v); a1 += us2f((u16)(v>>16));
      }
    }
    float sc = scale[d];
    float o0 = ((a0+b0)+(c0+e0))*sc;
    float o1 = ((a1+b1)+(c1+e1))*sc;
    if (bias){ o0 += bias[lane*2]; o1 += bias[lane*2+1]; }
    if (relu){ o0 = fmaxf(o0,0.f); o1 = fmaxf(o1,0.f); }
    if (OUTBF){
      ((uint*)out)[(size_t)d*64 + lane] = (uint)f2bu(o0) | ((uint)f2bu(o1) << 16);
    } else {
      ((float2*)out)[(size_t)d*64 + lane] = make_float2(o0, o1);
    }
  } else { // F == 64
    float a=0,b=0,c=0,e=0;
    if (SELF) a = us2f(h[(size_t)d*64 + lane]);
    for (int base = 0; base < n; base += 64){
      int mm = n - base; if (mm > 64) mm = 64;
      int idx = (lane < mm) ? csr[k0 + base + lane] : 0;
      int jj = 0;
      for (; jj + 4 <= mm; jj += 4){
        int s0=__shfl(idx,jj), s1=__shfl(idx,jj+1), s2=__shfl(idx,jj+2), s3=__shfl(idx,jj+3);
        a += us2f(h[(size_t)s0*64 + lane]);
        b += us2f(h[(size_t)s1*64 + lane]);
        c += us2f(h[(size_t)s2*64 + lane]);
        e += us2f(h[(size_t)s3*64 + lane]);
      }
      for (; jj < mm; ++jj){
        int s = __shfl(idx, jj);
        a += us2f(h[(size_t)s*64 + lane]);
      }
    }
    float o = ((a+b)+(c+e))*scale[d];
    if (bias) o += bias[lane];
    if (relu) o = fmaxf(o, 0.f);
    if (OUTBF) ((u16*)out)[(size_t)d*64 + lane] = f2bu(o);
    else       ((float*)out)[(size_t)d*64 + lane] = o;
  }
}

// ---------------- phase kernels ----------------
__global__ __launch_bounds__(256) void k_pA(const u16* xb, const u16* gW1t,
    const float* dinv, u16* BAb){
  gemm_body<256,128>(xb, gW1t, nullptr, dinv, BAb, 0, blockIdx.x);
}
__global__ __launch_bounds__(256) void k_pB(const u16* xb, const u16* hW1t,
    const float* hb1f, u16* BEb,
    const int* rp_g, const int* cg, const int* csr_g, const float* dinv,
    const u16* BAb, const float* gb1f, u16* BBb){
  if (blockIdx.x < 782) gemm_body<256,128>(xb, hW1t, hb1f, nullptr, BEb, 0, blockIdx.x);
  else gather_body<128,true,true>(rp_g, cg, csr_g, dinv, BAb, gb1f, BBb, 1, blockIdx.x - 782);
}
__global__ __launch_bounds__(256) void k_pC(const u16* BBb, const u16* gW2t,
    const float* dinv, u16* BAb,
    const int* rp_e, const int* ce, const int* csr_e, const float* inve,
    const u16* BEb, u16* BDb){
  if (blockIdx.x < 782) gemm_body<128,64>(BBb, gW2t, nullptr, dinv, BAb, 0, blockIdx.x);
  else gather_body<128,true,false>(rp_e, ce, csr_e, inve, BEb, nullptr, BDb, 0, blockIdx.x - 782);
}
__global__ __launch_bounds__(256) void k_pD(
    const int* rp_v, const int* cv, const int* csr_v, const float* invv,
    const u16* BDb, u16* BCb,
    const int* rp_g, const int* cg, const int* csr_g, const float* dinv,
    const u16* BAb, const float* gb2f, float* x2f){
  if (blockIdx.x < 12500) gather_body<128,true,false>(rp_v, cv, csr_v, invv, BDb, nullptr, BCb, 1, blockIdx.x);
  else gather_body<64,false,true>(rp_g, cg, csr_g, dinv, BAb, gb2f, x2f, 0, blockIdx.x - 12500);
}
__global__ __launch_bounds__(256) void k_pE(const u16* BCb, const u16* hW2t,
    const float* hb2f, u16* BEb){
  gemm_body<128,64>(BCb, hW2t, hb2f, nullptr, BEb, 0, blockIdx.x);
}
__global__ __launch_bounds__(256) void k_pF(const int* rp_e, const int* ce,
    const int* csr_e, const float* inve, const u16* BEb, u16* BDb){
  gather_body<64,true,false>(rp_e, ce, csr_e, inve, BEb, nullptr, BDb, 0, blockIdx.x);
}
// v2 gather + embeds fusion: x4 computed in-register, then v=0.5(x2+x4),
// wave-reduce norm, write embeds (d_out) + normalized dataf.
__global__ __launch_bounds__(256) void k_pG(const int* __restrict__ rp,
    const int* __restrict__ cnt, const int* __restrict__ csr,
    const float* __restrict__ invv, const u16* __restrict__ h,
    const float* __restrict__ x2f, void* __restrict__ out,
    float* __restrict__ dataf, const int* __restrict__ flag){
  const int wave = threadIdx.x >> 6, lane = threadIdx.x & 63;
  const int d = blockIdx.x*4 + wave;      // 12500*4 = 50000 rows exactly
  const int k0 = rp[d], n = cnt[d];
  float a=0,b=0,c=0,e=0;
  for (int base = 0; base < n; base += 64){
    int mm = n - base; if (mm > 64) mm = 64;
    int idx = (lane < mm) ? csr[k0 + base + lane] : 0;
    int jj = 0;
    for (; jj + 4 <= mm; jj += 4){
      int s0=__shfl(idx,jj), s1=__shfl(idx,jj+1), s2=__shfl(idx,jj+2), s3=__shfl(idx,jj+3);
      a += us2f(h[(size_t)s0*64 + lane]);
      b += us2f(h[(size_t)s1*64 + lane]);
      c += us2f(h[(size_t)s2*64 + lane]);
      e += us2f(h[(size_t)s3*64 + lane]);
    }
    for (; jj < mm; ++jj){
      int s = __shfl(idx, jj);
      a += us2f(h[(size_t)s*64 + lane]);
    }
  }
  float x4 = ((a+b)+(c+e))*invv[d];
  float v  = 0.5f*(x2f[(size_t)d*64 + lane] + x4);
  float ss = v*v;
  #pragma unroll
  for (int off=32; off>0; off>>=1) ss += __shfl_xor(ss, off);
  float inv = rsqrtf(ss);
  dataf[(size_t)d*64 + lane] = v*inv;
  stf(out, EMB_OFF + (size_t)d*64 + lane, v, flag[0]);
}

// ---------------- clustering ----------------
__global__ void k_mu_init(const float* __restrict__ data, float* __restrict__ mu){
  int p = threadIdx.x;      // 640 threads, 1 block
  int k = p >> 6, f = p & 63;
  mu[p] = data[(size_t)k*(NN/KCL)*64 + f];
}

__global__ __launch_bounds__(640) void k_cluster_iter(const float* __restrict__ data,
    const float* __restrict__ mu, float* __restrict__ part, float* __restrict__ pcr,
    const int* __restrict__ nit, int iter)
{
  if (iter >= nit[0]) return;
  __shared__ float ms[640];
  __shared__ float dt[64][65];
  __shared__ float ds[64][11];
  const int tid = threadIdx.x;
  ms[tid] = mu[tid];
  const int base = blockIdx.x*64;
  for (int i = tid; i < 4096; i += 640){
    int r = i >> 6, f = i & 63;
    int grow = base + r;
    dt[r][f] = (grow < NN) ? data[(size_t)grow*64 + f] : 0.f;
  }
  __syncthreads();
  {
    const int row = tid & 63, k = tid >> 6;
    float dot = 0.f;
    #pragma unroll 16
    for (int f = 0; f < 64; ++f)
      dot = fmaf(dt[row][f], ms[k*64 + f], dot);
    ds[row][k] = dot;
  }
  __syncthreads();
  if (tid < 64){
    float dot[KCL];
    #pragma unroll
    for (int k = 0; k < KCL; ++k) dot[k] = ds[tid][k];
    float m = -1e30f;
    #pragma unroll
    for (int k = 0; k < KCL; ++k) m = fmaxf(m, 5.0f*dot[k]);
    float s = 0.f, ev[KCL];
    #pragma unroll
    for (int k = 0; k < KCL; ++k){ ev[k] = expf(5.0f*dot[k]-m); s += ev[k]; }
    float inv = (base + tid < NN) ? 1.0f/s : 0.f;
    #pragma unroll
    for (int k = 0; k < KCL; ++k) ds[tid][k] = ev[k]*inv;
  }
  __syncthreads();
  {
    const int f = tid & 63, k = tid >> 6;
    float acc = 0.f, crp = 0.f;
    #pragma unroll 8
    for (int t = 0; t < 64; ++t){
      float rv = ds[t][k];
      acc = fmaf(rv, dt[t][f], acc);
      crp += rv;
    }
    part[(size_t)blockIdx.x*640 + tid] = acc;
    if (f == 0) pcr[blockIdx.x*16 + k] = crp;
  }
}

__global__ void k_cred1(const float* __restrict__ part, const float* __restrict__ pcr,
                        float* __restrict__ p2, float* __restrict__ pc2,
                        const int* __restrict__ nit, int iter){
  if (iter >= nit[0]) return;
  int b = blockIdx.x, t = threadIdx.x;
  int r0 = b*20, r1 = r0 + 20; if (r1 > CBLK) r1 = CBLK;
  if (t < 640){
    float a = 0.f;
    for (int r = r0; r < r1; ++r) a += part[(size_t)r*640 + t];
    p2[(size_t)b*640 + t] = a;
  } else if (t < 640 + KCL){
    int k = t - 640;
    float a = 0.f;
    for (int r = r0; r < r1; ++r) a += pcr[r*16 + k];
    pc2[b*16 + k] = a;
  }
}

__global__ void k_cred2mu(const float* __restrict__ p2, const float* __restrict__ pc2,
                          float* __restrict__ mu, const int* __restrict__ nit, int iter){
  if (iter >= nit[0]) return;
  __shared__ float crs[16];
  int t = threadIdx.x;
  if (t >= 640 && t < 640 + KCL){
    int k = t - 640;
    float a = 0.f;
    #pragma unroll
    for (int b = 0; b < 40; ++b) a += pc2[b*16 + k];
    crs[k] = a;
  }
  __syncthreads();
  if (t < 640){
    float a = 0.f;
    #pragma unroll
    for (int b = 0; b < 40; ++b) a += p2[(size_t)b*640 + t];
    mu[t] = a / crs[t >> 6];
  }
}

__global__ __launch_bounds__(640) void k_cluster_final(const float* __restrict__ data,
    const float* __restrict__ mu, void* __restrict__ out, const int* __restrict__ flag)
{
  __shared__ float ms[640];
  __shared__ float dt[64][65];
  __shared__ float ds[64][11];
  const int tid = threadIdx.x;
  ms[tid] = mu[tid];
  const int base = blockIdx.x*64;
  for (int i = tid; i < 4096; i += 640){
    int r = i >> 6, f = i & 63;
    int grow = base + r;
    dt[r][f] = (grow < NN) ? data[(size_t)grow*64 + f] : 0.f;
  }
  __syncthreads();
  {
    const int row = tid & 63, k = tid >> 6;
    float dot = 0.f;
    #pragma unroll 16
    for (int f = 0; f < 64; ++f)
      dot = fmaf(dt[row][f], ms[k*64 + f], dot);
    ds[row][k] = dot;
  }
  __syncthreads();
  const int isbf = flag[0];
  if (blockIdx.x == 0) stf(out, MU_OFF + tid, ms[tid], isbf);
  if (tid < 64 && base + tid < NN){
    const int row = base + tid;
    float dot[KCL];
    #pragma unroll
    for (int k = 0; k < KCL; ++k) dot[k] = ds[tid][k];
    float m = -1e30f;
    #pragma unroll
    for (int k = 0; k < KCL; ++k) m = fmaxf(m, 5.0f*dot[k]);
    float s = 0.f, ev[KCL];
    #pragma unroll
    for (int k = 0; k < KCL; ++k){ ev[k] = expf(5.0f*dot[k]-m); s += ev[k]; }
    float inv = 1.0f/s;
    #pragma unroll
    for (int k = 0; k < KCL; ++k){
      stf(out, (size_t)D_OFF + (size_t)row*KCL + k, dot[k],    isbf);
      stf(out, (size_t)R_OFF + (size_t)row*KCL + k, ev[k]*inv, isbf);
    }
  }
}

// ---------------- launch ----------------
extern "C" void kernel_launch(void* const* d_in, const int* in_sizes, int n_in,
                              void* d_out, int out_size, void* d_ws, size_t ws_size,
                              hipStream_t stream)
{
  const void* x   = d_in[0];
  const int*  ei  = (const int*)d_in[1];
  const int*  hv  = (const int*)d_in[2];
  const int*  he  = (const int*)d_in[3];
  const void* gW1 = d_in[4];
  const void* gb1 = d_in[5];
  const void* gW2 = d_in[6];
  const void* gb2 = d_in[7];
  const void* hW1 = d_in[8];
  const void* hb1 = d_in[9];
  const void* hW2 = d_in[10];
  const void* hb2 = d_in[11];
  const int*  nit = (const int*)d_in[12];

  float* ws = (float*)d_ws;
  size_t o = 0;
  u16*   xb  = (u16*)(ws + o); o += (size_t)NP*128;
  u16*   BAb = (u16*)(ws + o); o += (size_t)NP*64;
  u16*   BBb = (u16*)(ws + o); o += (size_t)NP*64;
  u16*   BCb = (u16*)(ws + o); o += (size_t)NP*64;
  u16*   BEb = (u16*)(ws + o); o += (size_t)NP*64;
  u16*   BDb = (u16*)(ws + o); o += (size_t)NEH*64;
  u16*  gW1t = (u16*)(ws + o); o += 16384;
  u16*  hW1t = (u16*)(ws + o); o += 16384;
  u16*  gW2t = (u16*)(ws + o); o += 4096;
  u16*  hW2t = (u16*)(ws + o); o += 4096;
  float* gb1f = ws + o; o += 128;
  float* hb1f = ws + o; o += 128;
  float* gb2f = ws + o; o += 64;
  float* hb2f = ws + o; o += 64;
  float* dinv = ws + o; o += 50048;
  float* invv = ws + o; o += 50048;
  float* inve = ws + o; o += 10048;
  float* mu   = ws + o; o += 640;
  float* part = ws + o; o += (size_t)CBLK*640;
  float* pcr  = ws + o; o += CBLK*16;
  float* p2   = ws + o; o += 40*640;
  float* pc2  = ws + o; o += 40*16;
  int*   dflg = (int*)(ws + o); o += 16;
  float* x2f   = (float*)xb;
  float* dataf = (float*)BBb;
  // int region (CSR)
  int* ib = (int*)(ws + o);
  size_t io = 0;
  int* cg    = ib + io; io += NN;
  int* cv    = ib + io; io += NN;
  int* ce    = ib + io; io += NEH + 48;
  int* rp_g  = ib + io; io += NN;
  int* rp_v  = ib + io; io += NN;
  int* rp_e  = ib + io; io += NEH + 48;
  int* csr_g = ib + io; io += EE;
  int* csr_e = ib + io; io += NINC;
  int* csr_v = ib + io; io += NINC;
  int* HAg   = ib + io; io += 128*250;
  int* HAv   = ib + io; io += 64*250;
  int* HAe   = ib + io; io += 64*250;
  int* bsg   = ib + io; io += 256;
  int* bsv   = ib + io; io += 256;
  int* bse   = ib + io; io += 256;
  u32* pg = (u32*)(ib + io); io += EE;
  u32* pv = (u32*)(ib + io); io += NINC;
  u32* pe = (u32*)(ib + io); io += NINC;

  const int* srcp = ei;
  const int* dstp = ei + EE;
  dim3 B(256);

  k_detect<<<dim3(1), B, 0, stream>>>((const u16*)x, dflg);
  k_prep<<<dim3(12628), B, 0, stream>>>(x, xb, gW1, hW1, gW2, hW2,
                                        gb1, hb1, gb2, hb2,
                                        gW1t, hW1t, gW2t, hW2t,
                                        gb1f, hb1f, gb2f, hb2f, dflg);

  k_hist_all <<<dim3(256), B, 0, stream>>>(dstp, hv, he, HAg, HAv, HAe);
  k_scanA_all<<<dim3(3),   B, 0, stream>>>(HAg, HAv, HAe, bsg, bsv, bse);
  k_fillA_all<<<dim3(256), B, 0, stream>>>(dstp, srcp, hv, he, HAg, HAv, HAe,
                                           bsg, bsv, bse, pg, pv, pe);
  k_fillB_all<<<dim3(750), B, 0, stream>>>(pg, pv, pe, bsg, bsv, bse,
                                           csr_g, csr_v, csr_e, cg, cv, ce,
                                           rp_g, rp_v, rp_e, dinv, invv, inve);

  k_pA<<<dim3(782),   B, 0, stream>>>(xb, gW1t, dinv, BAb);
  k_pB<<<dim3(13282), B, 0, stream>>>(xb, hW1t, hb1f, BEb,
                                      rp_g, cg, csr_g, dinv, BAb, gb1f, BBb);
  k_pC<<<dim3(3282),  B, 0, stream>>>(BBb, gW2t, dinv, BAb,
                                      rp_e, ce, csr_e, inve, BEb, BDb);
  k_pD<<<dim3(25000), B, 0, stream>>>(rp_v, cv, csr_v, invv, BDb, BCb,
                                      rp_g, cg, csr_g, dinv, BAb, gb2f, x2f);
  k_pE<<<dim3(782),   B, 0, stream>>>(BCb, hW2t, hb2f, BEb);
  k_pF<<<dim3(2500),  B, 0, stream>>>(rp_e, ce, csr_e, inve, BEb, BDb);
  k_pG<<<dim3(12500), B, 0, stream>>>(rp_v, cv, csr_v, invv, BDb,
                                      x2f, d_out, dataf, dflg);

  k_mu_init<<<dim3(1), dim3(640), 0, stream>>>(dataf, mu);
  for (int it = 0; it < 4; ++it){
    k_cluster_iter<<<dim3(CBLK), dim3(640), 0, stream>>>(dataf, mu, part, pcr, nit, it);
    k_cred1       <<<dim3(40),   dim3(768), 0, stream>>>(part, pcr, p2, pc2, nit, it);
    k_cred2mu     <<<dim3(1),    dim3(768), 0, stream>>>(p2, pc2, mu, nit, it);
  }
  k_cluster_final<<<dim3(CBLK), dim3(640), 0, stream>>>(dataf, mu, d_out, dflg);
}